// Round 1
// baseline (1995.015 us; speedup 1.0000x reference)
//
#include <hip/hip_runtime.h>
#include <cstdint>
#include <cstddef>

#define D_   384
#define Hn   6
#define HDm  64
#define T_   256
#define B_   128
#define NROW (B_ * T_)   // 32768

// ---------- helpers ----------
__device__ inline float bflo(uint32_t u) { return __uint_as_float(u << 16); }
__device__ inline float bfhi(uint32_t u) { return __uint_as_float(u & 0xFFFF0000u); }
__device__ inline uint32_t bf16rn(float f) {
  uint32_t u = __float_as_uint(f);
  return (u + 0x7FFFu + ((u >> 16) & 1u)) >> 16;
}

// ---------- LayerNorm: one 128-thread block per row ----------
__global__ __launch_bounds__(128) void ln_kernel(const float* __restrict__ x,
                                                 const float* __restrict__ g,
                                                 const float* __restrict__ b,
                                                 float* __restrict__ out) {
  int row = blockIdx.x, tid = threadIdx.x;
  const float* xr = x + (size_t)row * D_;
  float v0 = xr[tid], v1 = xr[tid + 128], v2 = xr[tid + 256];
  float s  = v0 + v1 + v2;
  float ss = v0 * v0 + v1 * v1 + v2 * v2;
#pragma unroll
  for (int off = 32; off > 0; off >>= 1) {
    s  += __shfl_down(s, off);
    ss += __shfl_down(ss, off);
  }
  __shared__ float red[4];
  if ((tid & 63) == 0) { red[(tid >> 6) * 2] = s; red[(tid >> 6) * 2 + 1] = ss; }
  __syncthreads();
  float S = red[0] + red[2], SS = red[1] + red[3];
  float mu  = S * (1.0f / D_);
  float var = SS * (1.0f / D_) - mu * mu;
  float inv = rsqrtf(var + 1e-5f);
  float* orow = out + (size_t)row * D_;
  orow[tid]         = (v0 - mu) * inv * g[tid]         + b[tid];
  orow[tid + 128]   = (v1 - mu) * inv * g[tid + 128]   + b[tid + 128];
  orow[tid + 256]   = (v2 - mu) * inv * g[tid + 256]   + b[tid + 256];
}

// ---------- pack Wq/Wk/Wv [H,D,HD] -> [D, 3*H*HD] = [384,1152] ----------
__global__ __launch_bounds__(256) void pack_qkv_w(const float* __restrict__ Wq,
                                                  const float* __restrict__ Wk,
                                                  const float* __restrict__ Wv,
                                                  float* __restrict__ Wo) {
  int idx = blockIdx.x * 256 + threadIdx.x;      // 442368 total
  if (idx >= D_ * 1152) return;
  int d = idx / 1152, col = idx % 1152;
  int which = col / 384, c2 = col % 384;
  int h = c2 / HDm, k = c2 % HDm;
  const float* W = (which == 0) ? Wq : (which == 1) ? Wk : Wv;
  Wo[idx] = W[((size_t)h * D_ + d) * HDm + k];
}

// ---------- generic fp32 GEMM: C[M,N] = A[M,K] @ W[K,N] (+bias)(relu)(+resid) ----------
// M%64==0, N%64==0, K%16==0 assumed.
__global__ __launch_bounds__(256) void gemm_kernel(const float* __restrict__ A,
                                                   const float* __restrict__ W,
                                                   const float* __restrict__ bias,
                                                   const float* __restrict__ resid,
                                                   float* __restrict__ C,
                                                   int M, int N, int K, int relu) {
  __shared__ float As[16][64];   // As[k][m]
  __shared__ float Bs[16][64];   // Bs[k][n]
  int tid = threadIdx.x;
  int bm = blockIdx.y * 64, bn = blockIdx.x * 64;
  int ty = tid / 16, tx = tid % 16;
  int am = tid / 4,  ak = (tid % 4) * 4;
  int wr = tid / 16, wc = (tid % 16) * 4;
  float acc[4][4] = {};
  for (int k0 = 0; k0 < K; k0 += 16) {
    float4 a4 = *(const float4*)&A[(size_t)(bm + am) * K + k0 + ak];
    As[ak + 0][am] = a4.x; As[ak + 1][am] = a4.y;
    As[ak + 2][am] = a4.z; As[ak + 3][am] = a4.w;
    *(float4*)&Bs[wr][wc] = *(const float4*)&W[(size_t)(k0 + wr) * N + bn + wc];
    __syncthreads();
#pragma unroll
    for (int kk = 0; kk < 16; ++kk) {
      float4 av = *(const float4*)&As[kk][ty * 4];
      float4 bv = *(const float4*)&Bs[kk][tx * 4];
      float a[4] = {av.x, av.y, av.z, av.w};
      float b[4] = {bv.x, bv.y, bv.z, bv.w};
#pragma unroll
      for (int i = 0; i < 4; ++i)
#pragma unroll
        for (int j = 0; j < 4; ++j) acc[i][j] += a[i] * b[j];
    }
    __syncthreads();
  }
#pragma unroll
  for (int i = 0; i < 4; ++i) {
    int r = bm + ty * 4 + i;
#pragma unroll
    for (int j = 0; j < 4; ++j) {
      int c = bn + tx * 4 + j;
      float v = acc[i][j];
      if (bias)  v += bias[c];
      if (relu)  v = fmaxf(v, 0.0f);
      if (resid) v += resid[(size_t)r * N + c];
      C[(size_t)r * N + c] = v;
    }
  }
}

// ---------- attention: one 256-thread block per (b,h); thread i = query row i ----------
// qkv layout: row (b*T+t), cols [0,384)=q(h*64+d), [384,768)=k, [768,1152)=v
__global__ __launch_bounds__(256) void attn_kernel(const float* __restrict__ qkv,
                                                   float* __restrict__ o) {
  __shared__ uint32_t Ks[T_ * 32];  // 32 KB, bf16 pairs
  __shared__ uint32_t Vs[T_ * 32];  // 32 KB
  int bh = blockIdx.x;
  int b = bh / Hn, h = bh % Hn;
  int tid = threadIdx.x;
  const float* base = qkv + (size_t)b * T_ * 1152;

  for (int idx = tid; idx < T_ * 32; idx += 256) {
    int s = idx >> 5, dp = idx & 31;
    const float* kp = base + (size_t)s * 1152 + 384 + h * HDm + dp * 2;
    Ks[idx] = bf16rn(kp[0]) | (bf16rn(kp[1]) << 16);
    const float* vp = kp + 384;
    Vs[idx] = bf16rn(vp[0]) | (bf16rn(vp[1]) << 16);
  }
  __syncthreads();

  int i = tid;  // query index
  float q[64];
  const float* qp = base + (size_t)i * 1152 + h * HDm;
#pragma unroll
  for (int d = 0; d < 64; d += 4) {
    float4 t = *(const float4*)&qp[d];
    q[d] = t.x; q[d + 1] = t.y; q[d + 2] = t.z; q[d + 3] = t.w;
  }
  float m = -INFINITY, l = 0.0f;
  float oacc[64];
#pragma unroll
  for (int d = 0; d < 64; ++d) oacc[d] = 0.0f;
  const float scale = 0.05103103630798288f;  // 1/sqrt(384)

  for (int s = 0; s <= i; ++s) {
    const uint32_t* kr = &Ks[s * 32];
    float xv = 0.0f;
#pragma unroll
    for (int dp = 0; dp < 32; dp += 4) {
      uint4 u = *(const uint4*)&kr[dp];
      xv += q[2*dp + 0] * bflo(u.x) + q[2*dp + 1] * bfhi(u.x)
          + q[2*dp + 2] * bflo(u.y) + q[2*dp + 3] * bfhi(u.y)
          + q[2*dp + 4] * bflo(u.z) + q[2*dp + 5] * bfhi(u.z)
          + q[2*dp + 6] * bflo(u.w) + q[2*dp + 7] * bfhi(u.w);
    }
    xv *= scale;
    if (xv > m) {
      float alpha = __expf(m - xv);  // first iter: exp(-inf)=0
      l *= alpha;
#pragma unroll
      for (int d = 0; d < 64; ++d) oacc[d] *= alpha;
      m = xv;
    }
    float p = __expf(xv - m);
    l += p;
    const uint32_t* vr = &Vs[s * 32];
#pragma unroll
    for (int dp = 0; dp < 32; dp += 4) {
      uint4 u = *(const uint4*)&vr[dp];
      oacc[2*dp + 0] += p * bflo(u.x); oacc[2*dp + 1] += p * bfhi(u.x);
      oacc[2*dp + 2] += p * bflo(u.y); oacc[2*dp + 3] += p * bfhi(u.y);
      oacc[2*dp + 4] += p * bflo(u.z); oacc[2*dp + 5] += p * bfhi(u.z);
      oacc[2*dp + 6] += p * bflo(u.w); oacc[2*dp + 7] += p * bfhi(u.w);
    }
  }
  float invl = 1.0f / l;
  float* op = o + ((size_t)b * T_ + i) * D_ + h * HDm;
#pragma unroll
  for (int d = 0; d < 64; d += 4) {
    float4 t = {oacc[d] * invl, oacc[d+1] * invl, oacc[d+2] * invl, oacc[d+3] * invl};
    *(float4*)&op[d] = t;
  }
}

extern "C" void kernel_launch(void* const* d_in, const int* in_sizes, int n_in,
                              void* d_out, int out_size, void* d_ws, size_t ws_size,
                              hipStream_t stream) {
  const float* x   = (const float*)d_in[0];
  const float* Wq  = (const float*)d_in[1];
  const float* Wk  = (const float*)d_in[2];
  const float* Wv  = (const float*)d_in[3];
  const float* Wp  = (const float*)d_in[4];
  const float* bp  = (const float*)d_in[5];
  const float* W1  = (const float*)d_in[6];
  const float* b1  = (const float*)d_in[7];
  const float* W2  = (const float*)d_in[8];
  const float* b2  = (const float*)d_in[9];
  const float* g1  = (const float*)d_in[10];
  const float* be1 = (const float*)d_in[11];
  const float* g2  = (const float*)d_in[12];
  const float* be2 = (const float*)d_in[13];
  float* out = (float*)d_out;

  // workspace layout (bytes):
  //  [0, 50331648)                     : h (LN output, reused for LN2)
  //  [50331648, 50331648+201326592)    : qkv (151MB) + o (50MB); later reused as ff1
  //  [251658240, +1769472)             : packed QKV weight [384,1152]
  char* ws = (char*)d_ws;
  float* hbuf = (float*)ws;
  float* qkv  = (float*)(ws + 50331648ull);
  float* ob   = (float*)(ws + 50331648ull + 150994944ull);
  float* ff1  = qkv;  // reuse whole 201MB region after attention+proj
  float* Wqkv = (float*)(ws + 251658240ull);

  // 1. pack QKV weights
  pack_qkv_w<<<1728, 256, 0, stream>>>(Wq, Wk, Wv, Wqkv);
  // 2. LN1
  ln_kernel<<<NROW, 128, 0, stream>>>(x, g1, be1, hbuf);
  // 3. QKV projection: [32768,384] @ [384,1152]
  gemm_kernel<<<dim3(1152 / 64, NROW / 64), 256, 0, stream>>>(
      hbuf, Wqkv, nullptr, nullptr, qkv, NROW, 1152, 384, 0);
  // 4. attention per (b,h)
  attn_kernel<<<B_ * Hn, 256, 0, stream>>>(qkv, ob);
  // 5. output projection + residual: x1 = x + o@Wp + bp  -> d_out
  gemm_kernel<<<dim3(384 / 64, NROW / 64), 256, 0, stream>>>(
      ob, Wp, bp, x, out, NROW, 384, 384, 0);
  // 6. LN2 on x1
  ln_kernel<<<NROW, 128, 0, stream>>>(out, g2, be2, hbuf);
  // 7. FF1 + ReLU: [32768,384] @ [384,1536]
  gemm_kernel<<<dim3(1536 / 64, NROW / 64), 256, 0, stream>>>(
      hbuf, W1, b1, nullptr, ff1, NROW, 1536, 384, 1);
  // 8. FF2 + residual: out = x1 + ff1@W2 + b2
  gemm_kernel<<<dim3(384 / 64, NROW / 64), 256, 0, stream>>>(
      ff1, W2, b2, out, out, NROW, 384, 1536, 0);
}

// Round 2
// 795.633 us; speedup vs baseline: 2.5075x; 2.5075x over previous
//
#include <hip/hip_runtime.h>
#include <cstdint>
#include <cstddef>

#define D_   384
#define Hn   6
#define HDm  64
#define T_   256
#define B_   128
#define NROW (B_ * T_)   // 32768

typedef __bf16  bf16x8 __attribute__((ext_vector_type(8)));
typedef float   f32x4  __attribute__((ext_vector_type(4)));
typedef const __attribute__((address_space(1))) void gvoid;
typedef __attribute__((address_space(3))) void lvoid;

// ---------- helpers ----------
__device__ inline float bflo(uint32_t u) { return __uint_as_float(u << 16); }
__device__ inline float bfhi(uint32_t u) { return __uint_as_float(u & 0xFFFF0000u); }
__device__ inline uint32_t bf16rn(float f) {
  uint32_t u = __float_as_uint(f);
  return (u + 0x7FFFu + ((u >> 16) & 1u)) >> 16;
}

// ---------- LayerNorm: fp32 in -> bf16 out, one 128-thread block per row ----------
__global__ __launch_bounds__(128) void ln_kernel(const float* __restrict__ x,
                                                 const float* __restrict__ g,
                                                 const float* __restrict__ b,
                                                 uint16_t* __restrict__ out) {
  int row = blockIdx.x, tid = threadIdx.x;
  const float* xr = x + (size_t)row * D_;
  float v0 = xr[tid], v1 = xr[tid + 128], v2 = xr[tid + 256];
  float s  = v0 + v1 + v2;
  float ss = v0 * v0 + v1 * v1 + v2 * v2;
#pragma unroll
  for (int off = 32; off > 0; off >>= 1) {
    s  += __shfl_down(s, off);
    ss += __shfl_down(ss, off);
  }
  __shared__ float red[4];
  if ((tid & 63) == 0) { red[(tid >> 6) * 2] = s; red[(tid >> 6) * 2 + 1] = ss; }
  __syncthreads();
  float S = red[0] + red[2], SS = red[1] + red[3];
  float mu  = S * (1.0f / D_);
  float var = SS * (1.0f / D_) - mu * mu;
  float inv = rsqrtf(var + 1e-5f);
  uint16_t* orow = out + (size_t)row * D_;
  orow[tid]       = (uint16_t)bf16rn((v0 - mu) * inv * g[tid]       + b[tid]);
  orow[tid + 128] = (uint16_t)bf16rn((v1 - mu) * inv * g[tid + 128] + b[tid + 128]);
  orow[tid + 256] = (uint16_t)bf16rn((v2 - mu) * inv * g[tid + 256] + b[tid + 256]);
}

// ---------- pack Wq/Wk/Wv [H,D,HD] -> bf16 Wt[col=1152][d=384] (K-contiguous) ----------
__global__ __launch_bounds__(256) void pack_qkv_w(const float* __restrict__ Wq,
                                                  const float* __restrict__ Wk,
                                                  const float* __restrict__ Wv,
                                                  uint16_t* __restrict__ Wo) {
  int idx = blockIdx.x * 256 + threadIdx.x;      // 1152*384 total
  if (idx >= 1152 * D_) return;
  int col = idx / D_, d = idx % D_;
  int which = col / 384, c2 = col % 384;
  int h = c2 / HDm, k = c2 % HDm;
  const float* W = (which == 0) ? Wq : (which == 1) ? Wk : Wv;
  Wo[idx] = (uint16_t)bf16rn(W[((size_t)h * D_ + d) * HDm + k]);
}

// ---------- transpose-pack W[K,N] -> bf16 Wt[N,K] ----------
__global__ __launch_bounds__(256) void pack_wt(const float* __restrict__ W,
                                               uint16_t* __restrict__ Wt,
                                               int K, int N) {
  int idx = blockIdx.x * 256 + threadIdx.x;
  if (idx >= K * N) return;
  int n = idx / K, k = idx % K;
  Wt[idx] = (uint16_t)bf16rn(W[(size_t)k * N + n]);
}

// ---------- bf16 MFMA GEMM: C[M,N] = A[M,K] @ Bt[N,K]^T (+bias)(relu)(+resid) ----------
// 128x128 tile, 4 waves, each wave 64x64 via 4x4 mfma_f32_16x16x32_bf16.
// M%128==0, N%128==0, K%32==0.
__global__ __launch_bounds__(256) void gemm_bf16(const uint16_t* __restrict__ A,
                                                 const uint16_t* __restrict__ Bt,
                                                 const float* __restrict__ bias,
                                                 const float* __restrict__ resid,
                                                 void* __restrict__ Cout,
                                                 int M, int N, int K,
                                                 int relu, int store_f32) {
  __shared__ uint16_t As[128 * 32];   // [m][k], 8 KB
  __shared__ uint16_t Bs[128 * 32];   // [n][k], 8 KB
  int tid = threadIdx.x;
  int bm = blockIdx.y * 128, bn = blockIdx.x * 128;
  int lane = tid & 63, wave = tid >> 6;
  int wm = (wave >> 1) << 6;          // 0 / 64
  int wn = (wave & 1) << 6;
  int lr = lane & 15;                 // row-within-16
  int lk = (lane >> 4) << 3;          // k offset 0/8/16/24
  int r0 = (lane >> 4) << 2;          // C row base within 16

  f32x4 acc[4][4];
  const f32x4 zero = {0.f, 0.f, 0.f, 0.f};
#pragma unroll
  for (int i = 0; i < 4; ++i)
#pragma unroll
    for (int j = 0; j < 4; ++j) acc[i][j] = zero;

  for (int k0 = 0; k0 < K; k0 += 32) {
    __syncthreads();   // previous iter's LDS reads done
#pragma unroll
    for (int t = 0; t < 2; ++t) {
      int c = t * 256 + tid;          // 16B chunk id, 512 per tile
      int row = c >> 2, kc = (c & 3) << 3;
      const uint16_t* ga = A  + (size_t)(bm + row) * K + (k0 + kc);
      const uint16_t* gb = Bt + (size_t)(bn + row) * K + (k0 + kc);
      __builtin_amdgcn_global_load_lds((gvoid*)ga, (lvoid*)((char*)As + c * 16), 16, 0, 0);
      __builtin_amdgcn_global_load_lds((gvoid*)gb, (lvoid*)((char*)Bs + c * 16), 16, 0, 0);
    }
    __syncthreads();   // staging complete (vmcnt drained by barrier)

    bf16x8 af[4], bfr[4];
#pragma unroll
    for (int i = 0; i < 4; ++i)
      af[i] = *(const bf16x8*)&As[(wm + i * 16 + lr) * 32 + lk];
#pragma unroll
    for (int j = 0; j < 4; ++j)
      bfr[j] = *(const bf16x8*)&Bs[(wn + j * 16 + lr) * 32 + lk];
#pragma unroll
    for (int i = 0; i < 4; ++i)
#pragma unroll
      for (int j = 0; j < 4; ++j)
        acc[i][j] = __builtin_amdgcn_mfma_f32_16x16x32_bf16(af[i], bfr[j], acc[i][j], 0, 0, 0);
  }

  // epilogue: C row = bm+wm+i*16+r0+r, col = bn+wn+j*16+lr
#pragma unroll
  for (int i = 0; i < 4; ++i) {
#pragma unroll
    for (int r = 0; r < 4; ++r) {
      int rr = bm + wm + i * 16 + r0 + r;
#pragma unroll
      for (int j = 0; j < 4; ++j) {
        int col = bn + wn + j * 16 + lr;
        float v = acc[i][j][r];
        if (bias)  v += bias[col];
        if (relu)  v = fmaxf(v, 0.0f);
        if (resid) v += resid[(size_t)rr * N + col];
        if (store_f32) ((float*)Cout)[(size_t)rr * N + col] = v;
        else           ((uint16_t*)Cout)[(size_t)rr * N + col] = (uint16_t)bf16rn(v);
      }
    }
  }
}

// ---------- attention: one 256-thread block per (b,h); thread i = query row i ----------
// qkv (bf16) row (b*T+t): cols [0,384)=q(h*64+d), [384,768)=k, [768,1152)=v
__global__ __launch_bounds__(256) void attn_kernel(const uint16_t* __restrict__ qkv,
                                                   uint16_t* __restrict__ o) {
  __shared__ uint32_t Ks[T_ * 32];  // 32 KB, bf16 pairs
  __shared__ uint32_t Vs[T_ * 32];  // 32 KB
  int bh = blockIdx.x;
  int b = bh / Hn, h = bh % Hn;
  int tid = threadIdx.x;
  const uint16_t* base = qkv + (size_t)b * T_ * 1152;

  for (int idx = tid; idx < T_ * 32; idx += 256) {
    int s = idx >> 5, dp = idx & 31;
    const uint16_t* kp = base + (size_t)s * 1152 + 384 + h * HDm + dp * 2;
    Ks[idx] = *(const uint32_t*)kp;
    Vs[idx] = *(const uint32_t*)(kp + 384);
  }
  __syncthreads();

  int i = tid;  // query index
  float q[64];
  const uint16_t* qp = base + (size_t)i * 1152 + h * HDm;
#pragma unroll
  for (int d = 0; d < 64; d += 8) {
    uint4 t = *(const uint4*)&qp[d];
    q[d]     = bflo(t.x); q[d + 1] = bfhi(t.x);
    q[d + 2] = bflo(t.y); q[d + 3] = bfhi(t.y);
    q[d + 4] = bflo(t.z); q[d + 5] = bfhi(t.z);
    q[d + 6] = bflo(t.w); q[d + 7] = bfhi(t.w);
  }
  float m = -INFINITY, l = 0.0f;
  float oacc[64];
#pragma unroll
  for (int d = 0; d < 64; ++d) oacc[d] = 0.0f;
  const float scale = 0.05103103630798288f;  // 1/sqrt(384)

  for (int s = 0; s <= i; ++s) {
    const uint32_t* kr = &Ks[s * 32];
    float xv = 0.0f;
#pragma unroll
    for (int dp = 0; dp < 32; dp += 4) {
      uint4 u = *(const uint4*)&kr[dp];
      xv += q[2*dp + 0] * bflo(u.x) + q[2*dp + 1] * bfhi(u.x)
          + q[2*dp + 2] * bflo(u.y) + q[2*dp + 3] * bfhi(u.y)
          + q[2*dp + 4] * bflo(u.z) + q[2*dp + 5] * bfhi(u.z)
          + q[2*dp + 6] * bflo(u.w) + q[2*dp + 7] * bfhi(u.w);
    }
    xv *= scale;
    if (xv > m) {
      float alpha = __expf(m - xv);
      l *= alpha;
#pragma unroll
      for (int d = 0; d < 64; ++d) oacc[d] *= alpha;
      m = xv;
    }
    float p = __expf(xv - m);
    l += p;
    const uint32_t* vr = &Vs[s * 32];
#pragma unroll
    for (int dp = 0; dp < 32; dp += 4) {
      uint4 u = *(const uint4*)&vr[dp];
      oacc[2*dp + 0] += p * bflo(u.x); oacc[2*dp + 1] += p * bfhi(u.x);
      oacc[2*dp + 2] += p * bflo(u.y); oacc[2*dp + 3] += p * bfhi(u.y);
      oacc[2*dp + 4] += p * bflo(u.z); oacc[2*dp + 5] += p * bfhi(u.z);
      oacc[2*dp + 6] += p * bflo(u.w); oacc[2*dp + 7] += p * bfhi(u.w);
    }
  }
  float invl = 1.0f / l;
  uint16_t* op = o + ((size_t)b * T_ + i) * D_ + h * HDm;
#pragma unroll
  for (int d = 0; d < 64; d += 2) {
    uint32_t pk = bf16rn(oacc[d] * invl) | (bf16rn(oacc[d + 1] * invl) << 16);
    *(uint32_t*)&op[d] = pk;
  }
}

extern "C" void kernel_launch(void* const* d_in, const int* in_sizes, int n_in,
                              void* d_out, int out_size, void* d_ws, size_t ws_size,
                              hipStream_t stream) {
  const float* x   = (const float*)d_in[0];
  const float* Wq  = (const float*)d_in[1];
  const float* Wk  = (const float*)d_in[2];
  const float* Wv  = (const float*)d_in[3];
  const float* Wp  = (const float*)d_in[4];
  const float* bp  = (const float*)d_in[5];
  const float* W1  = (const float*)d_in[6];
  const float* b1  = (const float*)d_in[7];
  const float* W2  = (const float*)d_in[8];
  const float* b2  = (const float*)d_in[9];
  const float* g1  = (const float*)d_in[10];
  const float* be1 = (const float*)d_in[11];
  const float* g2  = (const float*)d_in[12];
  const float* be2 = (const float*)d_in[13];
  float* out = (float*)d_out;

  // workspace layout (bytes), all bf16 activations:
  //  h    : [0, 25165824)
  //  qkv  : [25165824, 100663296)          (75.5 MB)
  //  ob   : [100663296, 125829120)         (25.2 MB)
  //  ff1  : reuse [25165824, 125829120)    (100.7 MB)
  //  Wqkvt: [125829120, +884736)
  //  Wpt  : [126713856, +294912)
  //  W1t  : [127008768, +1179648)
  //  W2t  : [128188416, +1179648)  -> end 129368064
  char* ws = (char*)d_ws;
  uint16_t* hbuf  = (uint16_t*)ws;
  uint16_t* qkv   = (uint16_t*)(ws + 25165824ull);
  uint16_t* ob    = (uint16_t*)(ws + 100663296ull);
  uint16_t* ff1   = qkv;
  uint16_t* Wqkvt = (uint16_t*)(ws + 125829120ull);
  uint16_t* Wpt   = (uint16_t*)(ws + 126713856ull);
  uint16_t* W1t   = (uint16_t*)(ws + 127008768ull);
  uint16_t* W2t   = (uint16_t*)(ws + 128188416ull);

  // 1. pack weights to bf16, K-contiguous
  pack_qkv_w<<<(1152 * D_ + 255) / 256, 256, 0, stream>>>(Wq, Wk, Wv, Wqkvt);
  pack_wt<<<(384 * 384 + 255) / 256, 256, 0, stream>>>(Wp, Wpt, 384, 384);
  pack_wt<<<(384 * 1536 + 255) / 256, 256, 0, stream>>>(W1, W1t, 384, 1536);
  pack_wt<<<(1536 * 384 + 255) / 256, 256, 0, stream>>>(W2, W2t, 1536, 384);
  // 2. LN1: x -> h (bf16)
  ln_kernel<<<NROW, 128, 0, stream>>>(x, g1, be1, hbuf);
  // 3. QKV projection: [32768,384] @ [384,1152] -> bf16
  gemm_bf16<<<dim3(1152 / 128, NROW / 128), 256, 0, stream>>>(
      hbuf, Wqkvt, nullptr, nullptr, qkv, NROW, 1152, 384, 0, 0);
  // 4. attention per (b,h) -> ob (bf16)
  attn_kernel<<<B_ * Hn, 256, 0, stream>>>(qkv, ob);
  // 5. x1 = x + ob@Wp + bp  -> d_out (fp32)
  gemm_bf16<<<dim3(384 / 128, NROW / 128), 256, 0, stream>>>(
      ob, Wpt, bp, x, out, NROW, 384, 384, 0, 1);
  // 6. LN2: x1 -> h (bf16)
  ln_kernel<<<NROW, 128, 0, stream>>>(out, g2, be2, hbuf);
  // 7. FF1 + ReLU: [32768,384] @ [384,1536] -> bf16
  gemm_bf16<<<dim3(1536 / 128, NROW / 128), 256, 0, stream>>>(
      hbuf, W1t, b1, nullptr, ff1, NROW, 1536, 384, 1, 0);
  // 8. out = x1 + ff1@W2 + b2 -> d_out (fp32)
  gemm_bf16<<<dim3(384 / 128, NROW / 128), 256, 0, stream>>>(
      ff1, W2t, b2, out, out, NROW, 384, 1536, 0, 1);
}

// Round 3
// 550.462 us; speedup vs baseline: 3.6243x; 1.4454x over previous
//
#include <hip/hip_runtime.h>
#include <cstdint>
#include <cstddef>

#define D_   384
#define Hn   6
#define HDm  64
#define T_   256
#define B_   128
#define NROW (B_ * T_)   // 32768

typedef __bf16  bf16x8 __attribute__((ext_vector_type(8)));
typedef float   f32x4  __attribute__((ext_vector_type(4)));
typedef const __attribute__((address_space(1))) void gvoid;
typedef __attribute__((address_space(3))) void lvoid;

// ---------- helpers ----------
__device__ inline uint32_t bf16rn(float f) {
  uint32_t u = __float_as_uint(f);
  return (u + 0x7FFFu + ((u >> 16) & 1u)) >> 16;
}

// ---------- LayerNorm: fp32 in -> bf16 out, one 128-thread block per row ----------
__global__ __launch_bounds__(128) void ln_kernel(const float* __restrict__ x,
                                                 const float* __restrict__ g,
                                                 const float* __restrict__ b,
                                                 uint16_t* __restrict__ out) {
  int row = blockIdx.x, tid = threadIdx.x;
  const float* xr = x + (size_t)row * D_;
  float v0 = xr[tid], v1 = xr[tid + 128], v2 = xr[tid + 256];
  float s  = v0 + v1 + v2;
  float ss = v0 * v0 + v1 * v1 + v2 * v2;
#pragma unroll
  for (int off = 32; off > 0; off >>= 1) {
    s  += __shfl_down(s, off);
    ss += __shfl_down(ss, off);
  }
  __shared__ float red[4];
  if ((tid & 63) == 0) { red[(tid >> 6) * 2] = s; red[(tid >> 6) * 2 + 1] = ss; }
  __syncthreads();
  float S = red[0] + red[2], SS = red[1] + red[3];
  float mu  = S * (1.0f / D_);
  float var = SS * (1.0f / D_) - mu * mu;
  float inv = rsqrtf(var + 1e-5f);
  uint16_t* orow = out + (size_t)row * D_;
  orow[tid]       = (uint16_t)bf16rn((v0 - mu) * inv * g[tid]       + b[tid]);
  orow[tid + 128] = (uint16_t)bf16rn((v1 - mu) * inv * g[tid + 128] + b[tid + 128]);
  orow[tid + 256] = (uint16_t)bf16rn((v2 - mu) * inv * g[tid + 256] + b[tid + 256]);
}

// ---------- pack Wq/Wk/Wv [H,D,HD] -> bf16 Wt[col=1152][d=384] (K-contiguous) ----------
__global__ __launch_bounds__(256) void pack_qkv_w(const float* __restrict__ Wq,
                                                  const float* __restrict__ Wk,
                                                  const float* __restrict__ Wv,
                                                  uint16_t* __restrict__ Wo) {
  int idx = blockIdx.x * 256 + threadIdx.x;      // 1152*384 total
  if (idx >= 1152 * D_) return;
  int col = idx / D_, d = idx % D_;
  int which = col / 384, c2 = col % 384;
  int h = c2 / HDm, k = c2 % HDm;
  const float* W = (which == 0) ? Wq : (which == 1) ? Wk : Wv;
  Wo[idx] = (uint16_t)bf16rn(W[((size_t)h * D_ + d) * HDm + k]);
}

// ---------- transpose-pack W[K,N] -> bf16 Wt[N,K] ----------
__global__ __launch_bounds__(256) void pack_wt(const float* __restrict__ W,
                                               uint16_t* __restrict__ Wt,
                                               int K, int N) {
  int idx = blockIdx.x * 256 + threadIdx.x;
  if (idx >= K * N) return;
  int n = idx / K, k = idx % K;
  Wt[idx] = (uint16_t)bf16rn(W[(size_t)k * N + n]);
}

// ---------- bf16 MFMA GEMM: C[M,N] = A[M,K] @ Bt[N,K]^T (+bias)(relu)(+resid) ----------
__global__ __launch_bounds__(256) void gemm_bf16(const uint16_t* __restrict__ A,
                                                 const uint16_t* __restrict__ Bt,
                                                 const float* __restrict__ bias,
                                                 const float* __restrict__ resid,
                                                 void* __restrict__ Cout,
                                                 int M, int N, int K,
                                                 int relu, int store_f32) {
  __shared__ uint16_t As[128 * 32];
  __shared__ uint16_t Bs[128 * 32];
  int tid = threadIdx.x;
  int bm = blockIdx.y * 128, bn = blockIdx.x * 128;
  int lane = tid & 63, wave = tid >> 6;
  int wm = (wave >> 1) << 6;
  int wn = (wave & 1) << 6;
  int lr = lane & 15;
  int lk = (lane >> 4) << 3;
  int r0 = (lane >> 4) << 2;

  f32x4 acc[4][4];
  const f32x4 zero = {0.f, 0.f, 0.f, 0.f};
#pragma unroll
  for (int i = 0; i < 4; ++i)
#pragma unroll
    for (int j = 0; j < 4; ++j) acc[i][j] = zero;

  for (int k0 = 0; k0 < K; k0 += 32) {
    __syncthreads();
#pragma unroll
    for (int t = 0; t < 2; ++t) {
      int c = t * 256 + tid;
      int row = c >> 2, kc = (c & 3) << 3;
      const uint16_t* ga = A  + (size_t)(bm + row) * K + (k0 + kc);
      const uint16_t* gb = Bt + (size_t)(bn + row) * K + (k0 + kc);
      __builtin_amdgcn_global_load_lds((gvoid*)ga, (lvoid*)((char*)As + c * 16), 16, 0, 0);
      __builtin_amdgcn_global_load_lds((gvoid*)gb, (lvoid*)((char*)Bs + c * 16), 16, 0, 0);
    }
    __syncthreads();

    bf16x8 af[4], bfr[4];
#pragma unroll
    for (int i = 0; i < 4; ++i)
      af[i] = *(const bf16x8*)&As[(wm + i * 16 + lr) * 32 + lk];
#pragma unroll
    for (int j = 0; j < 4; ++j)
      bfr[j] = *(const bf16x8*)&Bs[(wn + j * 16 + lr) * 32 + lk];
#pragma unroll
    for (int i = 0; i < 4; ++i)
#pragma unroll
      for (int j = 0; j < 4; ++j)
        acc[i][j] = __builtin_amdgcn_mfma_f32_16x16x32_bf16(af[i], bfr[j], acc[i][j], 0, 0, 0);
  }

#pragma unroll
  for (int i = 0; i < 4; ++i) {
#pragma unroll
    for (int r = 0; r < 4; ++r) {
      int rr = bm + wm + i * 16 + r0 + r;
#pragma unroll
      for (int j = 0; j < 4; ++j) {
        int col = bn + wn + j * 16 + lr;
        float v = acc[i][j][r];
        if (bias)  v += bias[col];
        if (relu)  v = fmaxf(v, 0.0f);
        if (resid) v += resid[(size_t)rr * N + col];
        if (store_f32) ((float*)Cout)[(size_t)rr * N + col] = v;
        else           ((uint16_t*)Cout)[(size_t)rr * N + col] = (uint16_t)bf16rn(v);
      }
    }
  }
}

// ---------- MFMA flash attention: one block per (b,h), 4 waves, wave w = rows w*64..w*64+63 ----------
// qkv (bf16) row (b*T+t): cols [0,384)=q(h*64+d), [384,768)=k, [768,1152)=v
__global__ __launch_bounds__(256, 2) void attn_mfma(const uint16_t* __restrict__ qkv,
                                                    uint16_t* __restrict__ o) {
  __shared__ uint16_t Kt[64 * 72];        // K-tile [s][d], pad 72 (9216 B)
  __shared__ uint16_t Vt[64 * 72];        // V-tile transposed [d][s], pad 72 (9216 B)
  __shared__ uint16_t Pb[4 * 64 * 72];    // per-wave P staging (36864 B)
  int bh = blockIdx.x;
  int b = bh / Hn, h = bh % Hn;
  int tid = threadIdx.x;
  int lane = tid & 63, w = tid >> 6;
  int ln = lane & 15, q = lane >> 4;
  int kq = q * 8;
  int m0 = w * 64;
  const uint16_t* base = qkv + (size_t)b * T_ * 1152;

  // Q fragments (A-layout): rows m0+i*16+ln, k = ks*32+kq
  bf16x8 af[4][2];
#pragma unroll
  for (int i = 0; i < 4; ++i)
#pragma unroll
    for (int ks = 0; ks < 2; ++ks)
      af[i][ks] = *(const bf16x8*)(base + (size_t)(m0 + i * 16 + ln) * 1152 + h * HDm + ks * 32 + kq);

  f32x4 o_[4][4], m_[4], l_[4];
  const f32x4 zero = {0.f, 0.f, 0.f, 0.f};
#pragma unroll
  for (int i = 0; i < 4; ++i) {
    m_[i] = {-1e30f, -1e30f, -1e30f, -1e30f};
    l_[i] = zero;
#pragma unroll
    for (int n = 0; n < 4; ++n) o_[i][n] = zero;
  }
  const float cs = 0.07362222f;  // (1/sqrt(384)) * log2(e)

  for (int jt = 0; jt < 4; ++jt) {
    if (jt) __syncthreads();    // all reads of Kt/Vt from previous tile done
    // --- stage K tile (64 rows x 64 d) ---
#pragma unroll
    for (int t = 0; t < 2; ++t) {
      int c = t * 256 + tid;                 // 512 chunks of 8 elems
      int s = c >> 3, d0 = (c & 7) << 3;
      *(uint4*)&Kt[s * 72 + d0] =
          *(const uint4*)(base + (size_t)(jt * 64 + s) * 1152 + 384 + h * HDm + d0);
    }
    // --- stage V tile transposed ---
    {
      int sv = tid & 63, dv = (tid >> 6) << 4;
      const uint16_t* gv = base + (size_t)(jt * 64 + sv) * 1152 + 768 + h * HDm + dv;
      uint16_t tmp[16];
      *(uint4*)&tmp[0] = *(const uint4*)gv;
      *(uint4*)&tmp[8] = *(const uint4*)(gv + 8);
#pragma unroll
      for (int jj = 0; jj < 16; ++jj) Vt[(dv + jj) * 72 + sv] = tmp[jj];
    }
    __syncthreads();

    if (w >= jt) {
      // --- S = Q K^T (64x64), C-layout: row=i*16+q*4+r, col=j*16+ln ---
      f32x4 s2[4][4];
#pragma unroll
      for (int i = 0; i < 4; ++i)
#pragma unroll
        for (int j = 0; j < 4; ++j) s2[i][j] = zero;
#pragma unroll
      for (int ks = 0; ks < 2; ++ks) {
        bf16x8 bf[4];
#pragma unroll
        for (int j = 0; j < 4; ++j)
          bf[j] = *(const bf16x8*)&Kt[(j * 16 + ln) * 72 + ks * 32 + kq];
#pragma unroll
        for (int i = 0; i < 4; ++i)
#pragma unroll
          for (int j = 0; j < 4; ++j)
            s2[i][j] = __builtin_amdgcn_mfma_f32_16x16x32_bf16(af[i][ks], bf[j], s2[i][j], 0, 0, 0);
      }
      // --- online softmax (base-2 domain) ---
#pragma unroll
      for (int i = 0; i < 4; ++i) {
#pragma unroll
        for (int j = 0; j < 4; ++j)
#pragma unroll
          for (int r = 0; r < 4; ++r) s2[i][j][r] *= cs;
        if (jt == w) {   // diagonal tile: mask col > row
#pragma unroll
          for (int j = 0; j < 4; ++j)
#pragma unroll
            for (int r = 0; r < 4; ++r)
              if (j * 16 + ln > i * 16 + q * 4 + r) s2[i][j][r] = -1e30f;
        }
        f32x4 rm;
#pragma unroll
        for (int r = 0; r < 4; ++r)
          rm[r] = fmaxf(fmaxf(s2[i][0][r], s2[i][1][r]), fmaxf(s2[i][2][r], s2[i][3][r]));
#pragma unroll
        for (int off = 1; off < 16; off <<= 1)
#pragma unroll
          for (int r = 0; r < 4; ++r)
            rm[r] = fmaxf(rm[r], __shfl_xor(rm[r], off));
        f32x4 mn, al, ps;
#pragma unroll
        for (int r = 0; r < 4; ++r) {
          mn[r] = fmaxf(m_[i][r], rm[r]);
          al[r] = exp2f(m_[i][r] - mn[r]);
          ps[r] = 0.f;
        }
        m_[i] = mn;
#pragma unroll
        for (int j = 0; j < 4; ++j)
#pragma unroll
          for (int r = 0; r < 4; ++r) {
            float p = exp2f(s2[i][j][r] - mn[r]);
            s2[i][j][r] = p;
            ps[r] += p;
          }
#pragma unroll
        for (int r = 0; r < 4; ++r) l_[i][r] = l_[i][r] * al[r] + ps[r];
#pragma unroll
        for (int n = 0; n < 4; ++n)
#pragma unroll
          for (int r = 0; r < 4; ++r) o_[i][n][r] *= al[r];
        // write P_i (C-layout -> LDS row-major)
#pragma unroll
        for (int j = 0; j < 4; ++j)
#pragma unroll
          for (int r = 0; r < 4; ++r)
            Pb[w * 4608 + (i * 16 + q * 4 + r) * 72 + j * 16 + ln] =
                (uint16_t)bf16rn(s2[i][j][r]);
      }
      // --- read P back in A-layout, O += P V ---
      bf16x8 pa[4][2];
#pragma unroll
      for (int i = 0; i < 4; ++i)
#pragma unroll
        for (int ks = 0; ks < 2; ++ks)
          pa[i][ks] = *(const bf16x8*)&Pb[w * 4608 + (i * 16 + ln) * 72 + ks * 32 + kq];
#pragma unroll
      for (int n = 0; n < 4; ++n) {
        bf16x8 bv0 = *(const bf16x8*)&Vt[(n * 16 + ln) * 72 + kq];
        bf16x8 bv1 = *(const bf16x8*)&Vt[(n * 16 + ln) * 72 + 32 + kq];
#pragma unroll
        for (int i = 0; i < 4; ++i) {
          o_[i][n] = __builtin_amdgcn_mfma_f32_16x16x32_bf16(pa[i][0], bv0, o_[i][n], 0, 0, 0);
          o_[i][n] = __builtin_amdgcn_mfma_f32_16x16x32_bf16(pa[i][1], bv1, o_[i][n], 0, 0, 0);
        }
      }
    }
  }
  // --- epilogue: row-sum l across the 16 col-lanes, normalize, store bf16 ---
#pragma unroll
  for (int i = 0; i < 4; ++i) {
    f32x4 lt = l_[i];
#pragma unroll
    for (int off = 1; off < 16; off <<= 1)
#pragma unroll
      for (int r = 0; r < 4; ++r) lt[r] += __shfl_xor(lt[r], off);
#pragma unroll
    for (int r = 0; r < 4; ++r) {
      float inv = 1.0f / lt[r];
      int row = b * T_ + m0 + i * 16 + q * 4 + r;
      uint16_t* op = o + (size_t)row * D_ + h * HDm;
#pragma unroll
      for (int n = 0; n < 4; ++n)
        op[n * 16 + ln] = (uint16_t)bf16rn(o_[i][n][r] * inv);
    }
  }
}

extern "C" void kernel_launch(void* const* d_in, const int* in_sizes, int n_in,
                              void* d_out, int out_size, void* d_ws, size_t ws_size,
                              hipStream_t stream) {
  const float* x   = (const float*)d_in[0];
  const float* Wq  = (const float*)d_in[1];
  const float* Wk  = (const float*)d_in[2];
  const float* Wv  = (const float*)d_in[3];
  const float* Wp  = (const float*)d_in[4];
  const float* bp  = (const float*)d_in[5];
  const float* W1  = (const float*)d_in[6];
  const float* b1  = (const float*)d_in[7];
  const float* W2  = (const float*)d_in[8];
  const float* b2  = (const float*)d_in[9];
  const float* g1  = (const float*)d_in[10];
  const float* be1 = (const float*)d_in[11];
  const float* g2  = (const float*)d_in[12];
  const float* be2 = (const float*)d_in[13];
  float* out = (float*)d_out;

  char* ws = (char*)d_ws;
  uint16_t* hbuf  = (uint16_t*)ws;
  uint16_t* qkv   = (uint16_t*)(ws + 25165824ull);
  uint16_t* ob    = (uint16_t*)(ws + 100663296ull);
  uint16_t* ff1   = qkv;
  uint16_t* Wqkvt = (uint16_t*)(ws + 125829120ull);
  uint16_t* Wpt   = (uint16_t*)(ws + 126713856ull);
  uint16_t* W1t   = (uint16_t*)(ws + 127008768ull);
  uint16_t* W2t   = (uint16_t*)(ws + 128188416ull);

  // 1. pack weights to bf16, K-contiguous
  pack_qkv_w<<<(1152 * D_ + 255) / 256, 256, 0, stream>>>(Wq, Wk, Wv, Wqkvt);
  pack_wt<<<(384 * 384 + 255) / 256, 256, 0, stream>>>(Wp, Wpt, 384, 384);
  pack_wt<<<(384 * 1536 + 255) / 256, 256, 0, stream>>>(W1, W1t, 384, 1536);
  pack_wt<<<(1536 * 384 + 255) / 256, 256, 0, stream>>>(W2, W2t, 1536, 384);
  // 2. LN1: x -> h (bf16)
  ln_kernel<<<NROW, 128, 0, stream>>>(x, g1, be1, hbuf);
  // 3. QKV projection: [32768,384] @ [384,1152] -> bf16
  gemm_bf16<<<dim3(1152 / 128, NROW / 128), 256, 0, stream>>>(
      hbuf, Wqkvt, nullptr, nullptr, qkv, NROW, 1152, 384, 0, 0);
  // 4. MFMA flash attention -> ob (bf16)
  attn_mfma<<<B_ * Hn, 256, 0, stream>>>(qkv, ob);
  // 5. x1 = x + ob@Wp + bp  -> d_out (fp32)
  gemm_bf16<<<dim3(384 / 128, NROW / 128), 256, 0, stream>>>(
      ob, Wpt, bp, x, out, NROW, 384, 384, 0, 1);
  // 6. LN2: x1 -> h (bf16)
  ln_kernel<<<NROW, 128, 0, stream>>>(out, g2, be2, hbuf);
  // 7. FF1 + ReLU: [32768,384] @ [384,1536] -> bf16
  gemm_bf16<<<dim3(1536 / 128, NROW / 128), 256, 0, stream>>>(
      hbuf, W1t, b1, nullptr, ff1, NROW, 1536, 384, 1, 0);
  // 8. out = x1 + ff1@W2 + b2 -> d_out (fp32)
  gemm_bf16<<<dim3(384 / 128, NROW / 128), 256, 0, stream>>>(
      ff1, W2t, b2, out, out, NROW, 384, 1536, 0, 1);
}